// Round 1
// baseline (565.358 us; speedup 1.0000x reference)
//
#include <hip/hip_runtime.h>
#include <hip/hip_bf16.h>

#define Bb 128
#define Tt 1024
#define Nn 128
#define Ss 256
#define NEGF (-1e30f)
#define DELTA 5.11f   // log(128)=4.852 + margin for max(trans)~0.21

// ---------------- kernel A: per-(b,t) row max over N ----------------
__global__ __launch_bounds__(256) void rowmax_kernel(const float* __restrict__ x,
                                                     float* __restrict__ maxx) {
    int row  = (blockIdx.x << 2) + (threadIdx.x >> 6);  // 4 waves per block, 1 row/wave
    int lane = threadIdx.x & 63;
    const float2* p = (const float2*)(x + (size_t)row * Nn);
    float2 v = p[lane];
    float m = fmaxf(v.x, v.y);
    #pragma unroll
    for (int o = 32; o > 0; o >>= 1) m = fmaxf(m, __shfl_xor(m, o));
    if (lane == 0) maxx[row] = m;
}

// ---------------- main: FCC (blocks 0..127) + FAC (blocks 128..255) ----------------
__global__ __launch_bounds__(256) void asg_main(
    const float* __restrict__ trans, const float* __restrict__ x,
    const int* __restrict__ targets, const int* __restrict__ ilen,
    const int* __restrict__ tlen, const float* __restrict__ maxx,
    float* __restrict__ fcc_out, float* __restrict__ fac_out)
{
    __shared__ float u[Nn];        // scaled alpha: u = exp(alpha - c)
    __shared__ float sp[Nn * 5];   // partial sums [j][q], stride-5 pad (gcd(5,32)=1)
    __shared__ float mxl[Tt];      // per-t row max (FCC)
    __shared__ float wred[2];      // cross-wave reduce scratch
    __shared__ float bsh[Ss];      // FAC beta shift buffer
    __shared__ float xr[Nn];       // FAC staged x row

    const int tid = threadIdx.x;
    const int bid = blockIdx.x;
    const int q    = tid >> 6;     // wave id
    const int lane = tid & 63;

    if (bid < Bb) {
        // ============ FCC for batch bid ============
        const int b = bid;
        const int len = ilen[b];                    // steps t = 1 .. len-1
        const float* xb  = x + (size_t)b * Tt * Nn;
        const float* mxg = maxx + b * Tt;

        for (int i = tid; i < Tt; i += 256) mxl[i] = mxg[i];

        // E fragments: rows j0=lane, j1=lane+64, i in [32q, 32q+32)
        float e0[32], e1[32];
        {
            const float* r0 = trans + (size_t)lane * Nn + (q << 5);
            const float* r1 = trans + (size_t)(lane + 64) * Nn + (q << 5);
            #pragma unroll
            for (int k = 0; k < 32; ++k) e0[k] = __expf(r0[k]);
            #pragma unroll
            for (int k = 0; k < 32; ++k) e1[k] = __expf(r1[k]);
        }
        __syncthreads();

        float c = mxl[0];
        if (tid < Nn) u[tid] = __expf(xb[tid] - c);   // u0, max exactly 1

        // register prefetch ring: rows t..t+7 for threads<128 (j=tid)
        float xpre[8];
        if (tid < Nn) {
            #pragma unroll
            for (int k = 0; k < 8; ++k) {
                int r = 1 + k; if (r > Tt - 1) r = Tt - 1;
                xpre[k] = xb[(size_t)r * Nn + tid];
            }
        }
        __syncthreads();

        float invm = 1.0f, logm = 0.0f;
        int t = 1;

        while (t + 8 <= len) {                      // full chunks: steps t..t+7
            #pragma unroll
            for (int tt = 0; tt < 8; ++tt) {
                // ---- matvec phase (all 4 waves): s[j] += E[j, 32q..] . u[32q..]
                const float4* u4 = (const float4*)(u + (q << 5));
                float acc[4] = {0.f, 0.f, 0.f, 0.f};
                #pragma unroll
                for (int k = 0; k < 8; ++k) {
                    float4 uc = u4[k];
                    int a = k & 1;
                    acc[a]     = fmaf(e0[4*k+0], uc.x, acc[a]);
                    acc[a]     = fmaf(e0[4*k+1], uc.y, acc[a]);
                    acc[a]     = fmaf(e0[4*k+2], uc.z, acc[a]);
                    acc[a]     = fmaf(e0[4*k+3], uc.w, acc[a]);
                    acc[2 + a] = fmaf(e1[4*k+0], uc.x, acc[2 + a]);
                    acc[2 + a] = fmaf(e1[4*k+1], uc.y, acc[2 + a]);
                    acc[2 + a] = fmaf(e1[4*k+2], uc.z, acc[2 + a]);
                    acc[2 + a] = fmaf(e1[4*k+3], uc.w, acc[2 + a]);
                }
                sp[lane * 5 + q]        = acc[0] + acc[1];
                sp[(lane + 64) * 5 + q] = acc[2] + acc[3];
                __syncthreads();

                // ---- epilogue (waves 0-1): combine, scale, write u
                if (tid < Nn) {
                    const int j = tid;
                    float s_ = (sp[j*5+0] + sp[j*5+1]) + (sp[j*5+2] + sp[j*5+3]);
                    float mxv = mxl[t + tt];
                    float w = __expf(xpre[tt] - mxv - DELTA);
                    float un = w * s_ * invm;
                    c += mxv + DELTA + logm;
                    invm = 1.0f; logm = 0.0f;
                    u[j] = un;
                    if (tt == 7) {                  // measure renorm every 8 steps
                        float mm = un;
                        #pragma unroll
                        for (int o = 32; o > 0; o >>= 1) mm = fmaxf(mm, __shfl_xor(mm, o));
                        if (lane == 0) wred[q] = mm;
                    }
                    int r = t + tt + 8; if (r > Tt - 1) r = Tt - 1;
                    xpre[tt] = xb[(size_t)r * Nn + j];   // refill ring
                }
                __syncthreads();
                if (tt == 7 && tid < Nn) {          // apply at next step
                    float mm = fmaxf(wred[0], wred[1]);
                    invm = 1.0f / mm;
                    logm = __logf(mm);
                }
            }
            t += 8;
        }
        // tail (< 8 steps, direct x loads)
        while (t < len) {
            const float4* u4 = (const float4*)(u + (q << 5));
            float acc[4] = {0.f, 0.f, 0.f, 0.f};
            #pragma unroll
            for (int k = 0; k < 8; ++k) {
                float4 uc = u4[k];
                int a = k & 1;
                acc[a]     = fmaf(e0[4*k+0], uc.x, acc[a]);
                acc[a]     = fmaf(e0[4*k+1], uc.y, acc[a]);
                acc[a]     = fmaf(e0[4*k+2], uc.z, acc[a]);
                acc[a]     = fmaf(e0[4*k+3], uc.w, acc[a]);
                acc[2 + a] = fmaf(e1[4*k+0], uc.x, acc[2 + a]);
                acc[2 + a] = fmaf(e1[4*k+1], uc.y, acc[2 + a]);
                acc[2 + a] = fmaf(e1[4*k+2], uc.z, acc[2 + a]);
                acc[2 + a] = fmaf(e1[4*k+3], uc.w, acc[2 + a]);
            }
            sp[lane * 5 + q]        = acc[0] + acc[1];
            sp[(lane + 64) * 5 + q] = acc[2] + acc[3];
            __syncthreads();
            if (tid < Nn) {
                const int j = tid;
                float s_ = (sp[j*5+0] + sp[j*5+1]) + (sp[j*5+2] + sp[j*5+3]);
                float mxv = mxl[t];
                float xv = xb[(size_t)t * Nn + j];
                float w = __expf(xv - mxv - DELTA);
                float un = w * s_ * invm;
                c += mxv + DELTA + logm;
                invm = 1.0f; logm = 0.0f;
                u[j] = un;
            }
            __syncthreads();
            ++t;
        }
        // fcc = c + log(sum_j u[j])
        if (tid < Nn) {
            float v = u[tid];
            #pragma unroll
            for (int o = 32; o > 0; o >>= 1) v += __shfl_xor(v, o);
            if (lane == 0) wred[q] = v;
        }
        __syncthreads();
        if (tid == 0) fcc_out[b] = c + __logf(wred[0] + wred[1]);
    } else {
        // ============ FAC for batch bid-128 ============
        const int b = bid - Bb;
        const int len = ilen[b];
        const int tl  = tlen[b];
        const float* xb = x + (size_t)b * Tt * Nn;
        const int s = tid;
        int tg = targets[b * Ss + s];
        int pg = (s == 0) ? tg : targets[b * Ss + s - 1];
        float st = trans[tg * Nn + tg];   // stay score
        float nt = trans[tg * Nn + pg];   // advance score
        float beta = (s == 0) ? xb[tg] : NEGF;

        float xpre[8];
        if (tid < Nn) {
            #pragma unroll
            for (int k = 0; k < 8; ++k) {
                int r = 1 + k; if (r > Tt - 1) r = Tt - 1;
                xpre[k] = xb[(size_t)r * Nn + tid];
            }
        }

        int t = 1;
        while (t + 8 <= len) {
            #pragma unroll
            for (int tt = 0; tt < 8; ++tt) {
                bsh[s] = beta;
                if (tid < Nn) xr[tid] = xpre[tt];
                __syncthreads();
                float bp = (s == 0) ? NEGF : bsh[s - 1];
                float em = xr[tg];
                float aa = beta + st;
                float bb2 = bp + nt;
                float hi = fmaxf(aa, bb2);
                float lo = fminf(aa, bb2);
                beta = em + hi + log1pf(__expf(lo - hi));
                if (tid < Nn) {
                    int r = t + tt + 8; if (r > Tt - 1) r = Tt - 1;
                    xpre[tt] = xb[(size_t)r * Nn + tid];
                }
                __syncthreads();
            }
            t += 8;
        }
        while (t < len) {
            bsh[s] = beta;
            if (tid < Nn) xr[tid] = xb[(size_t)t * Nn + tid];
            __syncthreads();
            float bp = (s == 0) ? NEGF : bsh[s - 1];
            float em = xr[tg];
            float aa = beta + st;
            float bb2 = bp + nt;
            float hi = fmaxf(aa, bb2);
            float lo = fminf(aa, bb2);
            beta = em + hi + log1pf(__expf(lo - hi));
            __syncthreads();
            ++t;
        }
        if (s == tl - 1) fac_out[b] = beta;
    }
}

// ---------------- final: mean(fcc - fac) ----------------
__global__ __launch_bounds__(128) void reduce_kernel(const float* __restrict__ fcc,
                                                     const float* __restrict__ fac,
                                                     float* __restrict__ out) {
    __shared__ float r2[2];
    int tid = threadIdx.x;
    float v = fcc[tid] - fac[tid];
    #pragma unroll
    for (int o = 32; o > 0; o >>= 1) v += __shfl_xor(v, o);
    if ((tid & 63) == 0) r2[tid >> 6] = v;
    __syncthreads();
    if (tid == 0) out[0] = (r2[0] + r2[1]) * (1.0f / Bb);
}

extern "C" void kernel_launch(void* const* d_in, const int* in_sizes, int n_in,
                              void* d_out, int out_size, void* d_ws, size_t ws_size,
                              hipStream_t stream) {
    const float* trans   = (const float*)d_in[0];
    const float* x       = (const float*)d_in[1];
    const int*   targets = (const int*)d_in[2];
    const int*   ilen    = (const int*)d_in[3];
    const int*   tlen    = (const int*)d_in[4];
    float* out = (float*)d_out;

    float* maxx = (float*)d_ws;          // B*T floats
    float* fcc  = maxx + Bb * Tt;        // B floats
    float* fac  = fcc + Bb;              // B floats

    rowmax_kernel<<<Bb * Tt / 4, 256, 0, stream>>>(x, maxx);
    asg_main<<<2 * Bb, 256, 0, stream>>>(trans, x, targets, ilen, tlen, maxx, fcc, fac);
    reduce_kernel<<<1, 128, 0, stream>>>(fcc, fac, out);
}